// Round 1
// baseline (594.174 us; speedup 1.0000x reference)
//
#include <hip/hip_runtime.h>
#include <hip/hip_bf16.h>
#include <math.h>

// Problem constants
#define B 32
#define N 128
#define BT (B*N)          // 4096
#define WD 100
#define UD 25
#define D 125             // LSTM hidden per direction
#define G4 (4*D)          // 500 gates
#define H2 (2*D)          // 250
#define HID 100
#define L 50

// Fast, overflow-safe activations on v_exp_f32
__device__ __forceinline__ float fast_tanh(float x) {
    float e = __expf(2.0f * x);
    return 1.0f - 2.0f / (e + 1.0f);
}
__device__ __forceinline__ float fast_sigmoid(float x) {
    return 1.0f / (1.0f + __expf(-x));
}
__device__ __forceinline__ float bcast_lane(float v, int k) {
    return __builtin_bit_cast(float, __builtin_amdgcn_readlane(__builtin_bit_cast(int, v), k));
}

// 64-way macro repetition
#define REP64(X) \
 X(0) X(1) X(2) X(3) X(4) X(5) X(6) X(7) X(8) X(9) \
 X(10) X(11) X(12) X(13) X(14) X(15) X(16) X(17) X(18) X(19) \
 X(20) X(21) X(22) X(23) X(24) X(25) X(26) X(27) X(28) X(29) \
 X(30) X(31) X(32) X(33) X(34) X(35) X(36) X(37) X(38) X(39) \
 X(40) X(41) X(42) X(43) X(44) X(45) X(46) X(47) X(48) X(49) \
 X(50) X(51) X(52) X(53) X(54) X(55) X(56) X(57) X(58) X(59) \
 X(60) X(61) X(62) X(63)

// ---------------------------------------------------------------------------
// K_setup: ONE launch for {12 weight transposes, embedding gather, fused
// biases, WhT pad-row zeroing}. Grid partition: [0,TR) transpose tiles,
// [TR,TR+2048) embed (2 bt/block), then 9 bias blocks, then 24 pad blocks.
// ---------------------------------------------------------------------------
struct TJob { const float* src; float* dst; int R, C, ldo, coff, tile0, tiles_x; };
struct TArgs { TJob j[12]; };

__global__ __launch_bounds__(256)
void setup_fused(TArgs a, int n_tr,
                 const int* __restrict__ wids, const int* __restrict__ uids,
                 const float* __restrict__ wl, const float* __restrict__ tl,
                 float* __restrict__ words,
                 const float* __restrict__ l0f_b, const float* __restrict__ l0b_b,
                 const float* __restrict__ l1f_b, const float* __restrict__ l1b_b,
                 const float* __restrict__ eh_b, const float* __restrict__ em_b,
                 const float* __restrict__ lm_b,
                 float* __restrict__ b_l0, float* __restrict__ b_l1,
                 float* __restrict__ b_s3,
                 float* __restrict__ p0, float* __restrict__ p1,
                 float* __restrict__ p2, float* __restrict__ p3) {
    __shared__ float tile[32][33];
    int bid = blockIdx.x;
    int tid = threadIdx.x;
    if (bid < n_tr) {                    // ---- transpose tiles ----
        int ji = 0;
        #pragma unroll
        for (int i = 1; i < 12; i++) if (bid >= a.j[i].tile0) ji = i;
        TJob jb = a.j[ji];
        int t = bid - jb.tile0;
        int tx = t % jb.tiles_x, ty = t / jb.tiles_x;
        int txx = tid & 31, tyy = tid >> 5;      // 32 x 8
        int k0 = tx*32, n0 = ty*32;
        #pragma unroll
        for (int dy = 0; dy < 32; dy += 8) {
            int n = n0 + tyy + dy, k = k0 + txx;
            if (n < jb.R && k < jb.C)
                tile[tyy+dy][txx] = jb.src[(size_t)n*jb.C + k];
        }
        __syncthreads();
        #pragma unroll
        for (int dy = 0; dy < 32; dy += 8) {
            int k = k0 + tyy + dy, n = n0 + txx;
            if (k < jb.C && n < jb.R)
                jb.dst[(size_t)k*jb.ldo + jb.coff + n] = tile[txx][tyy+dy];
        }
        return;
    }
    bid -= n_tr;
    if (bid < 2048) {                    // ---- embed: 2 bt per block ----
        int bt = bid*2 + (tid >> 7);
        int t = tid & 127;
        int wid = wids[bt], uid = uids[bt];
        if (t < WD)       words[bt*D + t] = wl[(size_t)wid*WD + t];
        else if (t < D)   words[bt*D + t] = tl[(size_t)uid*UD + (t - WD)];
        return;
    }
    bid -= 2048;
    if (bid < 9) {                       // ---- fused biases ----
        int t = bid*256 + tid;
        if (t < 500)        b_l0[t] = l0f_b[t];
        else if (t < 1000)  b_l0[t] = l0b_b[t-500];
        else if (t < 1500)  b_l1[t-1000] = l1f_b[t-1000];
        else if (t < 2000)  b_l1[t-1000] = l1b_b[t-1500];
        else if (t < 2100)  b_s3[t-2000] = eh_b[t-2000];
        else if (t < 2200)  b_s3[t-2000] = em_b[t-2100];
        else if (t < 2300)  b_s3[t-2000] = lm_b[t-2200];
        return;
    }
    bid -= 9;                            // ---- pad-row zeroing (24 blocks) ----
    int e = bid*256 + tid;               // < 6144; need 4*1516 = 6064
    if (e < 6064) {
        int m = e / 1516, o = e % 1516;
        float* p = (m == 0) ? p0 : (m == 1) ? p1 : (m == 2) ? p2 : p3;
        p[125*500 + o] = 0.0f;
    }
}

// ---------------------------------------------------------------------------
// K2: projection GEMM, transposed weights, CPT columns per thread,
//     software-pipelined WT loads (prefetch next k-group).
// ---------------------------------------------------------------------------
#define MT 16
template<int CPT, int BD>
__device__ __forceinline__
void proj_body(const float* __restrict__ x, const float* __restrict__ WT,
               const float* __restrict__ bias, float* __restrict__ out,
               int Ncols, int K, int ldx, const int* __restrict__ gather_idx,
               int blk, float* xs) {
    int m0 = blk * MT;
    for (int e = threadIdx.x; e < MT * K; e += BD) {
        int r = e / K, k = e - r * K;
        int m = m0 + r;
        int row = m;
        if (gather_idx) {
            int bb = m >> 7, np = m & 127;
            row = (bb << 7) + (np == 0 ? 0 : gather_idx[m]);
        }
        xs[k*17 + r] = x[(size_t)row*ldx + k];
    }
    __syncthreads();
    int n0 = threadIdx.x;
    int lane = threadIdx.x & 63;
    float acc[CPT][MT];
    int ncl[CPT];
    #pragma unroll
    for (int j = 0; j < CPT; j++) {
        int n = n0 + j*BD;
        ncl[j] = (n < Ncols) ? n : (Ncols - 1);
        #pragma unroll
        for (int r = 0; r < MT; r++) acc[j][r] = 0.0f;
    }
    float wkc[4][CPT];
    #pragma unroll
    for (int q = 0; q < 4; q++)
        #pragma unroll
        for (int j = 0; j < CPT; j++)
            wkc[q][j] = WT[(size_t)q*Ncols + ncl[j]];
    int k0 = 0;
    for (; k0 + 8 <= K; k0 += 4) {
        float xv = xs[(k0 + (lane >> 4))*17 + (lane & 15)];
        float wkn[4][CPT];
        #pragma unroll
        for (int q = 0; q < 4; q++)
            #pragma unroll
            for (int j = 0; j < CPT; j++)
                wkn[q][j] = WT[(size_t)(k0 + 4 + q)*Ncols + ncl[j]];
        #pragma unroll
        for (int q = 0; q < 4; q++) {
            #pragma unroll
            for (int r = 0; r < 16; r++) {
                float hv = bcast_lane(xv, q*16 + r);
                #pragma unroll
                for (int j = 0; j < CPT; j++)
                    acc[j][r] = fmaf(wkc[q][j], hv, acc[j][r]);
            }
        }
        #pragma unroll
        for (int q = 0; q < 4; q++)
            #pragma unroll
            for (int j = 0; j < CPT; j++)
                wkc[q][j] = wkn[q][j];
    }
    { // last full group
        float xv = xs[(k0 + (lane >> 4))*17 + (lane & 15)];
        #pragma unroll
        for (int q = 0; q < 4; q++) {
            #pragma unroll
            for (int r = 0; r < 16; r++) {
                float hv = bcast_lane(xv, q*16 + r);
                #pragma unroll
                for (int j = 0; j < CPT; j++)
                    acc[j][r] = fmaf(wkc[q][j], hv, acc[j][r]);
            }
        }
        k0 += 4;
    }
    for (; k0 < K; k0++) {
        float xv = xs[k0*17 + (lane & 15)];
        float wk[CPT];
        #pragma unroll
        for (int j = 0; j < CPT; j++) wk[j] = WT[(size_t)k0*Ncols + ncl[j]];
        #pragma unroll
        for (int r = 0; r < 16; r++) {
            float hv = bcast_lane(xv, r);
            #pragma unroll
            for (int j = 0; j < CPT; j++)
                acc[j][r] = fmaf(wk[j], hv, acc[j][r]);
        }
    }
    #pragma unroll
    for (int j = 0; j < CPT; j++) {
        int n = n0 + j*BD;
        if (n < Ncols) {
            float bb = bias[n];
            #pragma unroll
            for (int r = 0; r < MT; r++) out[(size_t)(m0 + r)*Ncols + n] = acc[j][r] + bb;
        }
    }
}

__global__ __launch_bounds__(512)
void proj_t(const float* __restrict__ x, const float* __restrict__ WT,
            const float* __restrict__ bias, float* __restrict__ out,
            int Ncols, int K, int ldx) {
    __shared__ float xs[250 * 17 + 16];
    proj_body<2, 512>(x, WT, bias, out, Ncols, K, ldx, nullptr, blockIdx.x, xs);
}

// fused scorer projections: blocks [0,256) -> s3 (Ncols=300), [256,512) -> lh
__global__ __launch_bounds__(256)
void proj_s3lh(const float* __restrict__ x,
               const float* __restrict__ WTa, const float* __restrict__ ba,
               float* __restrict__ outa,
               const float* __restrict__ WTb, const float* __restrict__ bb,
               float* __restrict__ outb, const int* __restrict__ gather_idx) {
    __shared__ float xs[250 * 17 + 16];
    int job = blockIdx.x >> 8;
    int blk = blockIdx.x & 255;
    if (job == 0)
        proj_body<2, 256>(x, WTa, ba, outa, 300, H2, H2, nullptr, blk, xs);
    else
        proj_body<2, 256>(x, WTb, bb, outb, 100, H2, H2, gather_idx, blk, xs);
}

// ---------------------------------------------------------------------------
// K3: LSTM scan — round-8 version verbatim (best measured: 140 us).
// ---------------------------------------------------------------------------
__global__ __launch_bounds__(1024, 4)
void lstm_scan(const float* __restrict__ xgc,
               const float* __restrict__ WhTf, const float* __restrict__ WhTb,
               float* __restrict__ out) {
    int dir = blockIdx.x & 1;
    int b = blockIdx.x >> 1;
    const float* WhT = dir ? WhTb : WhTf;   // [128][500], zero-padded rows 125..127
    int off = dir ? D : 0;
    int t = threadIdx.x;
    int g = t & 511;
    int half = t >> 9;
    int kbase = half << 6;                  // 0 or 64

    __shared__ __align__(16) float hbuf[128];
    __shared__ float pbuf[1024];

    unsigned voff0 = ((unsigned)kbase * 500u + (unsigned)g) * 4u;
#define DECLW(i) float w##i; \
    asm volatile("global_load_dword %0, %1, %2" \
                 : "=v"(w##i) : "v"(voff0 + (unsigned)(i)*2000u), "s"(WhT));
    REP64(DECLW)
#undef DECLW
    asm volatile("s_waitcnt vmcnt(0)" ::: "memory");

    float c = 0.0f;
    if (t < 128) hbuf[t] = 0.0f;
    __syncthreads();

    const float* xb = xgc + (size_t)b * N * 1000 + dir * 500;
    bool xa = (half == 0) && (g < G4);
    float x_next = xa ? xb[(size_t)(dir ? (N-1) : 0) * 1000 + g] : 0.0f;

    const float4* h4q = ((const float4*)hbuf) + (kbase >> 2);

#define FMA4(q, i0, i1, i2, i3) { float4 hv = h4q[q]; \
    a4[0] = fmaf(w##i0, hv.x, a4[0]); \
    a4[1] = fmaf(w##i1, hv.y, a4[1]); \
    a4[2] = fmaf(w##i2, hv.z, a4[2]); \
    a4[3] = fmaf(w##i3, hv.w, a4[3]); }

    for (int ti = 0; ti < N; ti++) {
        int tt = dir ? (N-1-ti) : ti;
        float x_cur = x_next;
        float xn = 0.0f;
        if (xa && ti + 1 < N)
            xn = xb[(size_t)(dir ? (tt-1) : (tt+1)) * 1000 + g];
        float a4[4];
        a4[0] = x_cur; a4[1] = 0.0f; a4[2] = 0.0f; a4[3] = 0.0f;
        FMA4(0,  0,  1,  2,  3)  FMA4(1,  4,  5,  6,  7)
        FMA4(2,  8,  9, 10, 11)  FMA4(3, 12, 13, 14, 15)
        FMA4(4, 16, 17, 18, 19)  FMA4(5, 20, 21, 22, 23)
        FMA4(6, 24, 25, 26, 27)  FMA4(7, 28, 29, 30, 31)
        FMA4(8, 32, 33, 34, 35)  FMA4(9, 36, 37, 38, 39)
        FMA4(10, 40, 41, 42, 43) FMA4(11, 44, 45, 46, 47)
        FMA4(12, 48, 49, 50, 51) FMA4(13, 52, 53, 54, 55)
        FMA4(14, 56, 57, 58, 59) FMA4(15, 60, 61, 62, 63)
        x_next = xn;
        pbuf[t] = (a4[0] + a4[1]) + (a4[2] + a4[3]);
        __syncthreads();
        if (t < D) {
            float iv = pbuf[t]       + pbuf[512 + t];
            float fv = pbuf[D+t]     + pbuf[512 + D+t];
            float gv = pbuf[2*D+t]   + pbuf[512 + 2*D+t];
            float ov = pbuf[3*D+t]   + pbuf[512 + 3*D+t];
            float si = fast_sigmoid(iv);
            float sf = fast_sigmoid(fv);
            float so = fast_sigmoid(ov);
            c = sf * c + si * fast_tanh(gv);
            float h = so * fast_tanh(c);
            hbuf[t] = h;
            out[(size_t)(b*N + tt)*H2 + off + t] = h;
        }
        __syncthreads();
    }
#undef FMA4
}

// ---------------------------------------------------------------------------
// K4: fused arc + rel. Blocks [0,1024): arc (b, 4-i tile); [1024,5120): rel.
// ---------------------------------------------------------------------------
#define ITILE 4
__global__ __launch_bounds__(128)
void arc_rel(const float* __restrict__ s3,
             const float* __restrict__ esW, const float* __restrict__ esb,
             const int* __restrict__ ta, const float* __restrict__ rh,
             const float* __restrict__ lsW, const float* __restrict__ lsb,
             float* __restrict__ arc_out, float* __restrict__ tree_out,
             float* __restrict__ rel_out, float* __restrict__ pred_out) {
    __shared__ float wms[128 * 101];
    __shared__ float whs[ITILE][HID];
    __shared__ float es[HID];
    __shared__ float sv[128];
    __shared__ int   si[128];
    int j = threadIdx.x;

    if (blockIdx.x < 1024) {             // ---------- arc ----------
        int blk = blockIdx.x;
        int b = blk >> 5, it = blk & 31;
        for (int e = j; e < 128 * HID; e += 128) {
            int r = e / HID, h = e - r * HID;
            wms[r*101 + h] = s3[(size_t)(b*N + r)*300 + 100 + h];
        }
        for (int e = j; e < ITILE * HID; e += 128) {
            int ii = e / HID, h = e - ii * HID;
            whs[ii][h] = s3[(size_t)(b*N + it*ITILE + ii)*300 + h];
        }
        if (j < HID) es[j] = esW[j];
        __syncthreads();
        float eb = esb[0];
        const float* wmr = &wms[j * 101];
        for (int ii = 0; ii < ITILE; ii++) {
            int i = it * ITILE + ii;
            int bi = b * N + i;
            float acc = 0.0f;
            for (int h = 0; h < HID; h++)
                acc = fmaf(es[h], fast_tanh(whs[ii][h] + wmr[h]), acc);
            int tai = (i == 0) ? 0 : ta[bi];
            float score = acc + eb + 1.0f - ((j == tai) ? 1.0f : 0.0f);
            arc_out[(size_t)bi*N + j] = score;
            sv[j] = score; si[j] = j;
            __syncthreads();
            for (int s = 64; s; s >>= 1) {
                if (j < s) {
                    float ov = sv[j+s]; int oi = si[j+s];
                    if (ov > sv[j] || (ov == sv[j] && oi < si[j])) { sv[j] = ov; si[j] = oi; }
                }
                __syncthreads();
            }
            if (j == 0) tree_out[bi] = (float)si[0];
            __syncthreads();
        }
    } else {                             // ---------- rel ----------
        int bt = blockIdx.x - 1024;
        float* tv = es;                  // reuse 100-float buffer
        if (j < HID)
            tv[j] = fast_tanh(s3[(size_t)bt*300 + 200 + j] + rh[(size_t)bt*HID + j]);
        __syncthreads();
        float score = -1e30f;
        if (j < L) {
            float acc = 0.0f;
            const float* wrow = lsW + j*HID;
            for (int h = 0; h < HID; h++) acc = fmaf(wrow[h], tv[h], acc);
            score = acc + lsb[j];
            rel_out[(size_t)bt*L + j] = score;
        }
        sv[j] = score; si[j] = j;
        __syncthreads();
        for (int s = 64; s; s >>= 1) {
            if (j < s) {
                float ov = sv[j+s]; int oi = si[j+s];
                if (ov > sv[j] || (ov == sv[j] && oi < si[j])) { sv[j] = ov; si[j] = oi; }
            }
            __syncthreads();
        }
        if (j == 0) pred_out[bt] = (float)si[0];
    }
}

// ---------------------------------------------------------------------------
extern "C" void kernel_launch(void* const* d_in, const int* in_sizes, int n_in,
                              void* d_out, int out_size, void* d_ws, size_t ws_size,
                              hipStream_t stream) {
    const int*   word_ids    = (const int*)  d_in[0];
    const int*   upos_ids    = (const int*)  d_in[1];
    const int*   target_arcs = (const int*)  d_in[2];
    const float* wlookup     = (const float*)d_in[3];
    const float* tlookup     = (const float*)d_in[4];
    const float* l0f_Wih = (const float*)d_in[5];
    const float* l0f_Whh = (const float*)d_in[6];
    const float* l0f_b   = (const float*)d_in[7];
    const float* l0b_Wih = (const float*)d_in[8];
    const float* l0b_Whh = (const float*)d_in[9];
    const float* l0b_b   = (const float*)d_in[10];
    const float* l1f_Wih = (const float*)d_in[11];
    const float* l1f_Whh = (const float*)d_in[12];
    const float* l1f_b   = (const float*)d_in[13];
    const float* l1b_Wih = (const float*)d_in[14];
    const float* l1b_Whh = (const float*)d_in[15];
    const float* l1b_b   = (const float*)d_in[16];
    const float* eh_W = (const float*)d_in[17];
    const float* eh_b = (const float*)d_in[18];
    const float* em_W = (const float*)d_in[19];
    const float* em_b = (const float*)d_in[20];
    const float* es_W = (const float*)d_in[21];
    const float* es_b = (const float*)d_in[22];
    const float* lh_W = (const float*)d_in[23];
    const float* lh_b = (const float*)d_in[24];
    const float* lm_W = (const float*)d_in[25];
    const float* lm_b = (const float*)d_in[26];
    const float* ls_W = (const float*)d_in[27];
    const float* ls_b = (const float*)d_in[28];

    float* out = (float*)d_out;
    float* trees_out = out;                         // 4096
    float* preds_out = out + BT;                    // 4096
    float* arc_out   = out + 2*BT;                  // 524288
    float* rel_out   = out + 2*BT + BT*N;           // 204800

    float* ws = (float*)d_ws;
    float* A       = ws;                    // 4,096,000: xg fused [m][1000]; later s3 [m][300]
    float* words   = ws + 4096000;          //   512,000
    float* C       = ws + 4608000;          // 1,024,000: h0, then ex
    float* WT_l0   = ws + 5632000;          //   125,000  [125][1000]
    float* WT_l1   = ws + 5757000;          //   250,000  [250][1000]
    float* WT_s3   = ws + 6007000;          //    75,000  [250][300]
    float* WT_lh   = ws + 6082000;          //    25,000  [250][100]
    float* WhT_l0f = ws + 6107000;          //    64,016  [128][500]+16 (pad rows zeroed)
    float* WhT_l0b = ws + 6171016;          //    64,016
    float* WhT_l1f = ws + 6235032;          //    64,016
    float* WhT_l1b = ws + 6299048;          //    64,016
    float* b_l0    = ws + 6363064;          //     1,000
    float* b_l1    = ws + 6364064;          //     1,000
    float* b_s3    = ws + 6365064;          //     1,000 (300 used)
    float* rel_head = ws + 6366064;         //   409,600  [m][100]
    // total 6,775,664 floats = 27.1 MB

    // 0. single fused setup launch
    TArgs ta{};
    int n_tr = 0;
    {
        auto tiles = [](int R, int C_) { return ((C_+31)/32) * ((R+31)/32); };
        struct { const float* s; float* d; int R, C, ldo, coff; } js[12] = {
            { l0f_Wih, WT_l0, 500, 125, 1000, 0 },
            { l0b_Wih, WT_l0, 500, 125, 1000, 500 },
            { l1f_Wih, WT_l1, 500, 250, 1000, 0 },
            { l1b_Wih, WT_l1, 500, 250, 1000, 500 },
            { eh_W, WT_s3, 100, 250, 300, 0 },
            { em_W, WT_s3, 100, 250, 300, 100 },
            { lm_W, WT_s3, 100, 250, 300, 200 },
            { lh_W, WT_lh, 100, 250, 100, 0 },
            { l0f_Whh, WhT_l0f, 500, 125, 500, 0 },
            { l0b_Whh, WhT_l0b, 500, 125, 500, 0 },
            { l1f_Whh, WhT_l1f, 500, 125, 500, 0 },
            { l1b_Whh, WhT_l1b, 500, 125, 500, 0 },
        };
        for (int i = 0; i < 12; i++) {
            ta.j[i].src = js[i].s;  ta.j[i].dst = js[i].d;
            ta.j[i].R = js[i].R;    ta.j[i].C = js[i].C;
            ta.j[i].ldo = js[i].ldo; ta.j[i].coff = js[i].coff;
            ta.j[i].tile0 = n_tr;
            ta.j[i].tiles_x = (js[i].C + 31) / 32;
            n_tr += tiles(js[i].R, js[i].C);
        }
    }
    setup_fused<<<n_tr + 2048 + 9 + 24, 256, 0, stream>>>(
        ta, n_tr, word_ids, upos_ids, wlookup, tlookup, words,
        l0f_b, l0b_b, l1f_b, l1b_b, eh_b, em_b, lm_b,
        b_l0, b_l1, b_s3, WhT_l0f, WhT_l0b, WhT_l1f, WhT_l1b);

    // 1. layer-0 input projections, fused fwd+bwd (K=125, N=1000)
    proj_t<<<BT/MT, 512, 0, stream>>>(words, WT_l0, b_l0, A, 1000, D, D);

    // 2. layer-0 scan -> h0 (C)
    lstm_scan<<<B*2, 1024, 0, stream>>>(A, WhT_l0f, WhT_l0b, C);

    // 3. layer-1 input projections (K=250, N=1000)
    proj_t<<<BT/MT, 512, 0, stream>>>(C, WT_l1, b_l1, A, 1000, H2, H2);

    // 4. layer-1 scan -> ex (C, overwrites h0)
    lstm_scan<<<B*2, 1024, 0, stream>>>(A, WhT_l1f, WhT_l1b, C);

    // 5. fused scorer projections: s3 (eh+em+lm, N=300) + lh gathered (N=100)
    proj_s3lh<<<512, 256, 0, stream>>>(C, WT_s3, b_s3, A,
                                       WT_lh, lh_b, rel_head, target_arcs);

    // 6. fused arc + rel scoring/argmax
    arc_rel<<<1024 + BT, 128, 0, stream>>>(A, es_W, es_b, target_arcs, rel_head,
                                           ls_W, ls_b, arc_out, trees_out,
                                           rel_out, preds_out);
}

// Round 2
// 558.190 us; speedup vs baseline: 1.0645x; 1.0645x over previous
//
#include <hip/hip_runtime.h>
#include <hip/hip_bf16.h>
#include <math.h>

// Problem constants
#define B 32
#define N 128
#define BT (B*N)          // 4096
#define WD 100
#define UD 25
#define D 125             // LSTM hidden per direction
#define G4 (4*D)          // 500 gates
#define H2 (2*D)          // 250
#define HID 100
#define L 50

// Fast, overflow-safe activations on v_exp_f32
__device__ __forceinline__ float fast_tanh(float x) {
    float e = __expf(2.0f * x);
    return 1.0f - 2.0f / (e + 1.0f);
}
__device__ __forceinline__ float fast_sigmoid(float x) {
    return 1.0f / (1.0f + __expf(-x));
}
__device__ __forceinline__ float bcast_lane(float v, int k) {
    return __builtin_bit_cast(float, __builtin_amdgcn_readlane(__builtin_bit_cast(int, v), k));
}

// ---------------------------------------------------------------------------
// K_setup: ONE launch for {12 weight transposes, embedding gather, fused
// biases, WhT pad zeroing}. Grid partition: [0,TR) transpose tiles,
// [TR,TR+2048) embed (2 bt/block), then 9 bias blocks, then 48 pad blocks.
// ---------------------------------------------------------------------------
struct TJob { const float* src; float* dst; int R, C, ldo, coff, tile0, tiles_x; };
struct TArgs { TJob j[12]; };

__global__ __launch_bounds__(256)
void setup_fused(TArgs a, int n_tr,
                 const int* __restrict__ wids, const int* __restrict__ uids,
                 const float* __restrict__ wl, const float* __restrict__ tl,
                 float* __restrict__ words,
                 const float* __restrict__ l0f_b, const float* __restrict__ l0b_b,
                 const float* __restrict__ l1f_b, const float* __restrict__ l1b_b,
                 const float* __restrict__ eh_b, const float* __restrict__ em_b,
                 const float* __restrict__ lm_b,
                 float* __restrict__ b_l0, float* __restrict__ b_l1,
                 float* __restrict__ b_s3,
                 float* __restrict__ p0, float* __restrict__ p1,
                 float* __restrict__ p2, float* __restrict__ p3) {
    __shared__ float tile[32][33];
    int bid = blockIdx.x;
    int tid = threadIdx.x;
    if (bid < n_tr) {                    // ---- transpose tiles ----
        int ji = 0;
        #pragma unroll
        for (int i = 1; i < 12; i++) if (bid >= a.j[i].tile0) ji = i;
        TJob jb = a.j[ji];
        int t = bid - jb.tile0;
        int tx = t % jb.tiles_x, ty = t / jb.tiles_x;
        int txx = tid & 31, tyy = tid >> 5;      // 32 x 8
        int k0 = tx*32, n0 = ty*32;
        #pragma unroll
        for (int dy = 0; dy < 32; dy += 8) {
            int n = n0 + tyy + dy, k = k0 + txx;
            if (n < jb.R && k < jb.C)
                tile[tyy+dy][txx] = jb.src[(size_t)n*jb.C + k];
        }
        __syncthreads();
        #pragma unroll
        for (int dy = 0; dy < 32; dy += 8) {
            int k = k0 + tyy + dy, n = n0 + txx;
            if (k < jb.C && n < jb.R)
                jb.dst[(size_t)k*jb.ldo + jb.coff + n] = tile[txx][tyy+dy];
        }
        return;
    }
    bid -= n_tr;
    if (bid < 2048) {                    // ---- embed: 2 bt per block ----
        int bt = bid*2 + (tid >> 7);
        int t = tid & 127;
        int wid = wids[bt], uid = uids[bt];
        if (t < WD)       words[bt*D + t] = wl[(size_t)wid*WD + t];
        else if (t < D)   words[bt*D + t] = tl[(size_t)uid*UD + (t - WD)];
        return;
    }
    bid -= 2048;
    if (bid < 9) {                       // ---- fused biases ----
        int t = bid*256 + tid;
        if (t < 500)        b_l0[t] = l0f_b[t];
        else if (t < 1000)  b_l0[t] = l0b_b[t-500];
        else if (t < 1500)  b_l1[t-1000] = l1f_b[t-1000];
        else if (t < 2000)  b_l1[t-1000] = l1b_b[t-1500];
        else if (t < 2100)  b_s3[t-2000] = eh_b[t-2000];
        else if (t < 2200)  b_s3[t-2000] = em_b[t-2100];
        else if (t < 2300)  b_s3[t-2000] = lm_b[t-2200];
        return;
    }
    bid -= 9;                            // ---- WhT pad zeroing (48 blocks) ----
    // WhT layout [128][512]: transpose fills k<125, col<500. Zero the rest:
    //   region A: k<125, col 500..511  (125*12 = 1500)
    //   region B: k 125..127, col 0..511 (3*512 = 1536)   total 3036 per buf
    int e = bid*256 + tid;               // < 12288; need 4*3036 = 12144
    if (e < 12144) {
        int m = e / 3036, o = e % 3036;
        float* p = (m == 0) ? p0 : (m == 1) ? p1 : (m == 2) ? p2 : p3;
        if (o < 1500) {
            int k = o / 12, cc = 500 + (o % 12);
            p[k*512 + cc] = 0.0f;
        } else {
            int o2 = o - 1500;
            p[(125 + (o2 >> 9))*512 + (o2 & 511)] = 0.0f;
        }
    }
}

// ---------------------------------------------------------------------------
// K2: projection GEMM, transposed weights, CPT columns per thread,
//     software-pipelined WT loads (prefetch next k-group).
// ---------------------------------------------------------------------------
#define MT 16
template<int CPT, int BD>
__device__ __forceinline__
void proj_body(const float* __restrict__ x, const float* __restrict__ WT,
               const float* __restrict__ bias, float* __restrict__ out,
               int Ncols, int K, int ldx, const int* __restrict__ gather_idx,
               int blk, float* xs) {
    int m0 = blk * MT;
    for (int e = threadIdx.x; e < MT * K; e += BD) {
        int r = e / K, k = e - r * K;
        int m = m0 + r;
        int row = m;
        if (gather_idx) {
            int bb = m >> 7, np = m & 127;
            row = (bb << 7) + (np == 0 ? 0 : gather_idx[m]);
        }
        xs[k*17 + r] = x[(size_t)row*ldx + k];
    }
    __syncthreads();
    int n0 = threadIdx.x;
    int lane = threadIdx.x & 63;
    float acc[CPT][MT];
    int ncl[CPT];
    #pragma unroll
    for (int j = 0; j < CPT; j++) {
        int n = n0 + j*BD;
        ncl[j] = (n < Ncols) ? n : (Ncols - 1);
        #pragma unroll
        for (int r = 0; r < MT; r++) acc[j][r] = 0.0f;
    }
    float wkc[4][CPT];
    #pragma unroll
    for (int q = 0; q < 4; q++)
        #pragma unroll
        for (int j = 0; j < CPT; j++)
            wkc[q][j] = WT[(size_t)q*Ncols + ncl[j]];
    int k0 = 0;
    for (; k0 + 8 <= K; k0 += 4) {
        float xv = xs[(k0 + (lane >> 4))*17 + (lane & 15)];
        float wkn[4][CPT];
        #pragma unroll
        for (int q = 0; q < 4; q++)
            #pragma unroll
            for (int j = 0; j < CPT; j++)
                wkn[q][j] = WT[(size_t)(k0 + 4 + q)*Ncols + ncl[j]];
        #pragma unroll
        for (int q = 0; q < 4; q++) {
            #pragma unroll
            for (int r = 0; r < 16; r++) {
                float hv = bcast_lane(xv, q*16 + r);
                #pragma unroll
                for (int j = 0; j < CPT; j++)
                    acc[j][r] = fmaf(wkc[q][j], hv, acc[j][r]);
            }
        }
        #pragma unroll
        for (int q = 0; q < 4; q++)
            #pragma unroll
            for (int j = 0; j < CPT; j++)
                wkc[q][j] = wkn[q][j];
    }
    { // last full group
        float xv = xs[(k0 + (lane >> 4))*17 + (lane & 15)];
        #pragma unroll
        for (int q = 0; q < 4; q++) {
            #pragma unroll
            for (int r = 0; r < 16; r++) {
                float hv = bcast_lane(xv, q*16 + r);
                #pragma unroll
                for (int j = 0; j < CPT; j++)
                    acc[j][r] = fmaf(wkc[q][j], hv, acc[j][r]);
            }
        }
        k0 += 4;
    }
    for (; k0 < K; k0++) {
        float xv = xs[k0*17 + (lane & 15)];
        float wk[CPT];
        #pragma unroll
        for (int j = 0; j < CPT; j++) wk[j] = WT[(size_t)k0*Ncols + ncl[j]];
        #pragma unroll
        for (int r = 0; r < 16; r++) {
            float hv = bcast_lane(xv, r);
            #pragma unroll
            for (int j = 0; j < CPT; j++)
                acc[j][r] = fmaf(wk[j], hv, acc[j][r]);
        }
    }
    #pragma unroll
    for (int j = 0; j < CPT; j++) {
        int n = n0 + j*BD;
        if (n < Ncols) {
            float bb = bias[n];
            #pragma unroll
            for (int r = 0; r < MT; r++) out[(size_t)(m0 + r)*Ncols + n] = acc[j][r] + bb;
        }
    }
}

__global__ __launch_bounds__(512)
void proj_t(const float* __restrict__ x, const float* __restrict__ WT,
            const float* __restrict__ bias, float* __restrict__ out,
            int Ncols, int K, int ldx) {
    __shared__ float xs[250 * 17 + 16];
    proj_body<2, 512>(x, WT, bias, out, Ncols, K, ldx, nullptr, blockIdx.x, xs);
}

// fused scorer projections: blocks [0,256) -> s3 (Ncols=300), [256,512) -> lh
__global__ __launch_bounds__(256)
void proj_s3lh(const float* __restrict__ x,
               const float* __restrict__ WTa, const float* __restrict__ ba,
               float* __restrict__ outa,
               const float* __restrict__ WTb, const float* __restrict__ bb,
               float* __restrict__ outb, const int* __restrict__ gather_idx) {
    __shared__ float xs[250 * 17 + 16];
    int job = blockIdx.x >> 8;
    int blk = blockIdx.x & 255;
    if (job == 0)
        proj_body<2, 256>(x, WTa, ba, outa, 300, H2, H2, nullptr, blk, xs);
    else
        proj_body<2, 256>(x, WTb, bb, outb, 100, H2, H2, gather_idx, blk, xs);
}

// ---------------------------------------------------------------------------
// K3: LSTM scan v2. 512 threads = 8 waves. Wave w: k-split ks=w>>1 (32 k's),
// col-group cg=(w&1)*64+lane, 4 contiguous cols per thread. Weights in 32
// float4 VGPRs. h distributed via 1 ds_read_b32 + v_readlane broadcast
// (VALU pipe) instead of 16 ds_read_b128 broadcasts (LDS return-BW bound).
// WhT layout [128][512], zero-padded rows 125-127 and cols 500-511.
// ---------------------------------------------------------------------------
__global__ __launch_bounds__(512)
void lstm_scan(const float* __restrict__ xgc,
               const float* __restrict__ WhTf, const float* __restrict__ WhTb,
               float* __restrict__ out) {
    int dir = blockIdx.x & 1;
    int b = blockIdx.x >> 1;
    const float* WhT = dir ? WhTb : WhTf;   // [128][512], zero-padded
    int off = dir ? D : 0;
    int t = threadIdx.x;
    int lane = t & 63;
    int w = t >> 6;                 // wave 0..7
    int ks = w >> 1;                // k-split 0..3
    int cg = ((w & 1) << 6) + lane; // col-group 0..127
    int c0 = cg << 2;               // first col 0..508

    __shared__ __align__(16) float hbuf[128];
    __shared__ __align__(16) float pbuf[4*512];

    // resident weights: wv[k] = WhT[ks*32+k][c0..c0+3]
    float4 wv[32];
    #pragma unroll
    for (int k = 0; k < 32; k++)
        wv[k] = *(const float4*)&WhT[(size_t)(ks*32 + k)*512 + c0];

    if (t < 128) hbuf[t] = 0.0f;
    __syncthreads();

    const float* xb = xgc + (size_t)b * N * 1000 + dir * 500;
    bool xa = (ks == 0) && (cg < 125);
    float4 x_next = make_float4(0.f, 0.f, 0.f, 0.f);
    if (xa) x_next = *(const float4*)&xb[(size_t)(dir ? (N-1) : 0)*1000 + c0];

    float c = 0.0f;
    for (int ti = 0; ti < N; ti++) {
        int tt = dir ? (N-1-ti) : ti;
        // seed this wave's h k-range: lanes 0-31 hold h[ks*32+0..31]
        float vh = hbuf[ks*32 + (lane & 31)];
        float4 x_cur = x_next;
        float4 xn = make_float4(0.f, 0.f, 0.f, 0.f);
        if (xa && ti + 1 < N)
            xn = *(const float4*)&xb[(size_t)(dir ? (tt-1) : (tt+1))*1000 + c0];
        float a0 = x_cur.x, a1 = x_cur.y, a2 = x_cur.z, a3 = x_cur.w;
        #pragma unroll
        for (int k = 0; k < 32; k++) {
            float hs = bcast_lane(vh, k);
            a0 = fmaf(wv[k].x, hs, a0);
            a1 = fmaf(wv[k].y, hs, a1);
            a2 = fmaf(wv[k].z, hs, a2);
            a3 = fmaf(wv[k].w, hs, a3);
        }
        x_next = xn;
        *(float4*)&pbuf[ks*512 + c0] = make_float4(a0, a1, a2, a3);
        __syncthreads();
        if (t < D) {
            float iv = pbuf[t]       + pbuf[512+t]       + pbuf[1024+t]       + pbuf[1536+t];
            float fv = pbuf[125+t]   + pbuf[512+125+t]   + pbuf[1024+125+t]   + pbuf[1536+125+t];
            float gv = pbuf[250+t]   + pbuf[512+250+t]   + pbuf[1024+250+t]   + pbuf[1536+250+t];
            float ov = pbuf[375+t]   + pbuf[512+375+t]   + pbuf[1024+375+t]   + pbuf[1536+375+t];
            float si = fast_sigmoid(iv);
            float sf = fast_sigmoid(fv);
            float so = fast_sigmoid(ov);
            c = sf * c + si * fast_tanh(gv);
            float h = so * fast_tanh(c);
            hbuf[t] = h;
            out[(size_t)(b*N + tt)*H2 + off + t] = h;
        }
        __syncthreads();
    }
}

// ---------------------------------------------------------------------------
// K4: fused arc + rel. Blocks [0,1024): arc (b, 4-i tile); [1024,5120): rel.
// ---------------------------------------------------------------------------
#define ITILE 4
__global__ __launch_bounds__(128)
void arc_rel(const float* __restrict__ s3,
             const float* __restrict__ esW, const float* __restrict__ esb,
             const int* __restrict__ ta, const float* __restrict__ rh,
             const float* __restrict__ lsW, const float* __restrict__ lsb,
             float* __restrict__ arc_out, float* __restrict__ tree_out,
             float* __restrict__ rel_out, float* __restrict__ pred_out) {
    __shared__ float wms[128 * 101];
    __shared__ float whs[ITILE][HID];
    __shared__ float es[HID];
    __shared__ float sv[128];
    __shared__ int   si[128];
    int j = threadIdx.x;

    if (blockIdx.x < 1024) {             // ---------- arc ----------
        int blk = blockIdx.x;
        int b = blk >> 5, it = blk & 31;
        for (int e = j; e < 128 * HID; e += 128) {
            int r = e / HID, h = e - r * HID;
            wms[r*101 + h] = s3[(size_t)(b*N + r)*300 + 100 + h];
        }
        for (int e = j; e < ITILE * HID; e += 128) {
            int ii = e / HID, h = e - ii * HID;
            whs[ii][h] = s3[(size_t)(b*N + it*ITILE + ii)*300 + h];
        }
        if (j < HID) es[j] = esW[j];
        __syncthreads();
        float eb = esb[0];
        const float* wmr = &wms[j * 101];
        for (int ii = 0; ii < ITILE; ii++) {
            int i = it * ITILE + ii;
            int bi = b * N + i;
            float acc = 0.0f;
            for (int h = 0; h < HID; h++)
                acc = fmaf(es[h], fast_tanh(whs[ii][h] + wmr[h]), acc);
            int tai = (i == 0) ? 0 : ta[bi];
            float score = acc + eb + 1.0f - ((j == tai) ? 1.0f : 0.0f);
            arc_out[(size_t)bi*N + j] = score;
            sv[j] = score; si[j] = j;
            __syncthreads();
            for (int s = 64; s; s >>= 1) {
                if (j < s) {
                    float ov = sv[j+s]; int oi = si[j+s];
                    if (ov > sv[j] || (ov == sv[j] && oi < si[j])) { sv[j] = ov; si[j] = oi; }
                }
                __syncthreads();
            }
            if (j == 0) tree_out[bi] = (float)si[0];
            __syncthreads();
        }
    } else {                             // ---------- rel ----------
        int bt = blockIdx.x - 1024;
        float* tv = es;                  // reuse 100-float buffer
        if (j < HID)
            tv[j] = fast_tanh(s3[(size_t)bt*300 + 200 + j] + rh[(size_t)bt*HID + j]);
        __syncthreads();
        float score = -1e30f;
        if (j < L) {
            float acc = 0.0f;
            const float* wrow = lsW + j*HID;
            for (int h = 0; h < HID; h++) acc = fmaf(wrow[h], tv[h], acc);
            score = acc + lsb[j];
            rel_out[(size_t)bt*L + j] = score;
        }
        sv[j] = score; si[j] = j;
        __syncthreads();
        for (int s = 64; s; s >>= 1) {
            if (j < s) {
                float ov = sv[j+s]; int oi = si[j+s];
                if (ov > sv[j] || (ov == sv[j] && oi < si[j])) { sv[j] = ov; si[j] = oi; }
            }
            __syncthreads();
        }
        if (j == 0) pred_out[bt] = (float)si[0];
    }
}

// ---------------------------------------------------------------------------
extern "C" void kernel_launch(void* const* d_in, const int* in_sizes, int n_in,
                              void* d_out, int out_size, void* d_ws, size_t ws_size,
                              hipStream_t stream) {
    const int*   word_ids    = (const int*)  d_in[0];
    const int*   upos_ids    = (const int*)  d_in[1];
    const int*   target_arcs = (const int*)  d_in[2];
    const float* wlookup     = (const float*)d_in[3];
    const float* tlookup     = (const float*)d_in[4];
    const float* l0f_Wih = (const float*)d_in[5];
    const float* l0f_Whh = (const float*)d_in[6];
    const float* l0f_b   = (const float*)d_in[7];
    const float* l0b_Wih = (const float*)d_in[8];
    const float* l0b_Whh = (const float*)d_in[9];
    const float* l0b_b   = (const float*)d_in[10];
    const float* l1f_Wih = (const float*)d_in[11];
    const float* l1f_Whh = (const float*)d_in[12];
    const float* l1f_b   = (const float*)d_in[13];
    const float* l1b_Wih = (const float*)d_in[14];
    const float* l1b_Whh = (const float*)d_in[15];
    const float* l1b_b   = (const float*)d_in[16];
    const float* eh_W = (const float*)d_in[17];
    const float* eh_b = (const float*)d_in[18];
    const float* em_W = (const float*)d_in[19];
    const float* em_b = (const float*)d_in[20];
    const float* es_W = (const float*)d_in[21];
    const float* es_b = (const float*)d_in[22];
    const float* lh_W = (const float*)d_in[23];
    const float* lh_b = (const float*)d_in[24];
    const float* lm_W = (const float*)d_in[25];
    const float* lm_b = (const float*)d_in[26];
    const float* ls_W = (const float*)d_in[27];
    const float* ls_b = (const float*)d_in[28];

    float* out = (float*)d_out;
    float* trees_out = out;                         // 4096
    float* preds_out = out + BT;                    // 4096
    float* arc_out   = out + 2*BT;                  // 524288
    float* rel_out   = out + 2*BT + BT*N;           // 204800

    float* ws = (float*)d_ws;
    float* A       = ws;                    // 4,096,000: xg fused [m][1000]; later s3 [m][300]
    float* words   = ws + 4096000;          //   512,000
    float* C       = ws + 4608000;          // 1,024,000: h0, then ex
    float* WT_l0   = ws + 5632000;          //   125,000  [125][1000]
    float* WT_l1   = ws + 5757000;          //   250,000  [250][1000]
    float* WT_s3   = ws + 6007000;          //    75,000  [250][300]
    float* WT_lh   = ws + 6082000;          //    25,000  [250][100]
    float* WhT_l0f = ws + 6107000;          //    65,536  [128][512] (pads zeroed)
    float* WhT_l0b = ws + 6172536;          //    65,536
    float* WhT_l1f = ws + 6238072;          //    65,536
    float* WhT_l1b = ws + 6303608;          //    65,536
    float* b_l0    = ws + 6369144;          //     1,000
    float* b_l1    = ws + 6370144;          //     1,000
    float* b_s3    = ws + 6371144;          //     1,000 (300 used)
    float* rel_head = ws + 6372144;         //   409,600  [m][100]
    // total 6,781,744 floats = 27.1 MB

    // 0. single fused setup launch
    TArgs ta{};
    int n_tr = 0;
    {
        auto tiles = [](int R, int C_) { return ((C_+31)/32) * ((R+31)/32); };
        struct { const float* s; float* d; int R, C, ldo, coff; } js[12] = {
            { l0f_Wih, WT_l0, 500, 125, 1000, 0 },
            { l0b_Wih, WT_l0, 500, 125, 1000, 500 },
            { l1f_Wih, WT_l1, 500, 250, 1000, 0 },
            { l1b_Wih, WT_l1, 500, 250, 1000, 500 },
            { eh_W, WT_s3, 100, 250, 300, 0 },
            { em_W, WT_s3, 100, 250, 300, 100 },
            { lm_W, WT_s3, 100, 250, 300, 200 },
            { lh_W, WT_lh, 100, 250, 100, 0 },
            { l0f_Whh, WhT_l0f, 500, 125, 512, 0 },
            { l0b_Whh, WhT_l0b, 500, 125, 512, 0 },
            { l1f_Whh, WhT_l1f, 500, 125, 512, 0 },
            { l1b_Whh, WhT_l1b, 500, 125, 512, 0 },
        };
        for (int i = 0; i < 12; i++) {
            ta.j[i].src = js[i].s;  ta.j[i].dst = js[i].d;
            ta.j[i].R = js[i].R;    ta.j[i].C = js[i].C;
            ta.j[i].ldo = js[i].ldo; ta.j[i].coff = js[i].coff;
            ta.j[i].tile0 = n_tr;
            ta.j[i].tiles_x = (js[i].C + 31) / 32;
            n_tr += tiles(js[i].R, js[i].C);
        }
    }
    setup_fused<<<n_tr + 2048 + 9 + 48, 256, 0, stream>>>(
        ta, n_tr, word_ids, upos_ids, wlookup, tlookup, words,
        l0f_b, l0b_b, l1f_b, l1b_b, eh_b, em_b, lm_b,
        b_l0, b_l1, b_s3, WhT_l0f, WhT_l0b, WhT_l1f, WhT_l1b);

    // 1. layer-0 input projections, fused fwd+bwd (K=125, N=1000)
    proj_t<<<BT/MT, 512, 0, stream>>>(words, WT_l0, b_l0, A, 1000, D, D);

    // 2. layer-0 scan -> h0 (C)
    lstm_scan<<<B*2, 512, 0, stream>>>(A, WhT_l0f, WhT_l0b, C);

    // 3. layer-1 input projections (K=250, N=1000)
    proj_t<<<BT/MT, 512, 0, stream>>>(C, WT_l1, b_l1, A, 1000, H2, H2);

    // 4. layer-1 scan -> ex (C, overwrites h0)
    lstm_scan<<<B*2, 512, 0, stream>>>(A, WhT_l1f, WhT_l1b, C);

    // 5. fused scorer projections: s3 (eh+em+lm, N=300) + lh gathered (N=100)
    proj_s3lh<<<512, 256, 0, stream>>>(C, WT_s3, b_s3, A,
                                       WT_lh, lh_b, rel_head, target_arcs);

    // 6. fused arc + rel scoring/argmax
    arc_rel<<<1024 + BT, 128, 0, stream>>>(A, es_W, es_b, target_arcs, rel_head,
                                           ls_W, ls_b, arc_out, trees_out,
                                           rel_out, preds_out);
}